// Round 2
// baseline (330.896 us; speedup 1.0000x reference)
//
#include <hip/hip_runtime.h>
#include <hip/hip_bf16.h>
#include <hip/hip_fp16.h>

// Bahdanau attention: B=32, T=4096, QD=VD=AD=256
// out = (c [32,256], a [32,4096]) fp32, concatenated flat.
//
// Round 2: single fused pass over values. Each wave stages its 32 rows of
// values (fp32->f16, XOR-swizzled, wave-private LDS), MFMAs e, exponentiates
// in-place (no max pass needed: |e| <= ~3), and does P.V from the staged LDS
// tile -- values is read from HBM exactly once (128 MB ~= 21 us floor).

#define BB 32
#define TT 4096
#define DD 256

typedef _Float16 half8  __attribute__((ext_vector_type(8)));
typedef _Float16 half4v __attribute__((ext_vector_type(4)));
typedef float f32x4  __attribute__((ext_vector_type(4)));
typedef float f32x16 __attribute__((ext_vector_type(16)));

// ---------------------------------------------------------------------------
// Kernel 0: prep.
//  blocks 0..31 : qp[b,a] = query[b,:].Wq[a,:] + bq[a] + bv[a]
//  blocks 32..63: Wv fp32 -> f16, pre-swizzled into MFMA B-fragment order:
//                 o8 = ((sg*8 + nt)*64 + lane): B[k][n], k = sg*16+(lane/32)*8+j,
//                 n = nt*32 + (lane%32)   (validated in round 1)
// ---------------------------------------------------------------------------
__global__ __launch_bounds__(256) void prep_kernel(
    const float* __restrict__ query, const float* __restrict__ Wq,
    const float* __restrict__ bq,    const float* __restrict__ Wv,
    const float* __restrict__ bv,
    float* __restrict__ qp, half8* __restrict__ wvfrag)
{
    int blk = blockIdx.x, tid = threadIdx.x;
    if (blk < BB) {
        __shared__ float ql[DD];
        ql[tid] = query[blk*DD + tid];
        __syncthreads();
        const f32x4* wr4 = (const f32x4*)(Wq + tid*DD);
        const f32x4* ql4 = (const f32x4*)ql;
        float s = 0.f;
        #pragma unroll 8
        for (int q = 0; q < DD/4; ++q) {
            f32x4 w4 = wr4[q];
            f32x4 x4 = ql4[q];
            s += w4[0]*x4[0] + w4[1]*x4[1] + w4[2]*x4[2] + w4[3]*x4[3];
        }
        qp[blk*DD + tid] = s + bq[tid] + bv[tid];
    } else {
        int o8 = (blk - BB)*256 + tid;      // 0..8191
        int L  = o8 & 63;
        int nt = (o8 >> 6) & 7;
        int sg = o8 >> 9;                   // 0..15
        int n  = nt*32 + (L & 31);
        int kb = sg*16 + (L >> 5)*8;
        const float* src = Wv + n*DD + kb;
        f32x4 s0 = *(const f32x4*)(src);
        f32x4 s1 = *(const f32x4*)(src + 4);
        half8 h;
        h[0]=(_Float16)s0[0]; h[1]=(_Float16)s0[1]; h[2]=(_Float16)s0[2]; h[3]=(_Float16)s0[3];
        h[4]=(_Float16)s1[0]; h[5]=(_Float16)s1[1]; h[6]=(_Float16)s1[2]; h[7]=(_Float16)s1[3];
        wvfrag[o8] = h;
    }
}

__device__ __forceinline__ float tanh_fast(float x) {
    float ex = __expf(2.f*x);
    return __builtin_fmaf(-2.f, __builtin_amdgcn_rcpf(ex + 1.f), 1.f);
}

// ---------------------------------------------------------------------------
// Kernel 1: fused e-GEMM + exp + P.V. 1024 blocks x 256 threads (4 waves).
// Wave w owns rows [blk*128 + w*32, +32). LDS: 4 wave-private 16KB V-tiles,
// f16, row pitch 512B = 32 x 16B groups, group g stored at g ^ (row&7).
// ---------------------------------------------------------------------------
__global__ __launch_bounds__(256, 2) void fused_kernel(
    const float* __restrict__ values, const half8* __restrict__ wvfrag,
    const float* __restrict__ qp,     const float* __restrict__ wvs,
    const float* __restrict__ bvs,    float* __restrict__ p_out,
    float* __restrict__ cout,         float* __restrict__ Ssum)
{
    __shared__ char Vraw[65536];

    int tid = threadIdx.x;
    int w = tid >> 6, L = tid & 63;
    int m = L & 31, kh = L >> 5;
    int row0 = blockIdx.x * 128;
    int b = row0 >> 12;

    char* Vw = Vraw + w*16384;                       // wave-private 16KB
    const float* gbase = values + (size_t)(row0 + w*32)*DD;

    // ---- stage: 32 rows x 256 k, coalesced f32x4 loads (16 lanes/row = 256B),
    //      cvt -> f16, swizzled ds_write_b64. All 32 loads issued up front.
    int srow = (/*G>>4*/ L >> 4);                    // G = j*64+L -> row = j*4 + (L>>4)
    int q    = L & 15;
    f32x4 ld[32];
    #pragma unroll
    for (int c = 0; c < 4; ++c)
        #pragma unroll
        for (int j = 0; j < 8; ++j)
            ld[c*8+j] = *(const f32x4*)(gbase + (j*4 + srow)*DD + c*64 + q*4);
    #pragma unroll
    for (int c = 0; c < 4; ++c)
        #pragma unroll
        for (int j = 0; j < 8; ++j) {
            int row = j*4 + srow;
            f32x4 v4 = ld[c*8+j];
            half4v h;
            h[0]=(_Float16)v4[0]; h[1]=(_Float16)v4[1];
            h[2]=(_Float16)v4[2]; h[3]=(_Float16)v4[3];
            int gs = (c*8 + (q>>1)) ^ (row & 7);
            *(half4v*)(Vw + row*512 + gs*16 + (q&1)*8) = h;
        }

    // ---- e-GEMM: N=256 in two halves (acc = 4 x f32x16 = 64 regs each)
    const half8* Vl8 = (const half8*)Vw;             // [row*32 + g]
    int gxor = m & 7;
    float part[16];
    #pragma unroll
    for (int r = 0; r < 16; ++r) part[r] = 0.f;

    #pragma unroll
    for (int hN = 0; hN < 2; ++hN) {
        f32x16 acc[4] = {};
        #pragma unroll
        for (int kk = 0; kk < 16; ++kk) {
            half8 af = Vl8[m*32 + ((kk*2 + kh) ^ gxor)];
            const half8* bp = wvfrag + (kk*8 + hN*4)*64 + L;
            #pragma unroll
            for (int nt2 = 0; nt2 < 4; ++nt2)
                acc[nt2] = __builtin_amdgcn_mfma_f32_32x32x16_f16(af, bp[nt2*64], acc[nt2], 0, 0, 0);
        }
        #pragma unroll
        for (int nt2 = 0; nt2 < 4; ++nt2) {
            int a0 = (hN*4 + nt2)*32 + m;
            float qv  = qp[b*DD + a0];
            float wvv = wvs[a0];
            #pragma unroll
            for (int r = 0; r < 16; ++r)
                part[r] += tanh_fast(acc[nt2][r] + qv) * wvv;
        }
    }

    // ---- reduce over the 32 a-lanes of each half; every lane gets all 16 sums
    #pragma unroll
    for (int r = 0; r < 16; ++r) {
        part[r] += __shfl_xor(part[r], 1);
        part[r] += __shfl_xor(part[r], 2);
        part[r] += __shfl_xor(part[r], 4);
        part[r] += __shfl_xor(part[r], 8);
        part[r] += __shfl_xor(part[r], 16);
    }

    // ---- p = exp(e) (no max subtraction: |e| <= ~3), write unnormalized p
    float bv0 = bvs[0];
    float pe[16];
    float sloc = 0.f;
    #pragma unroll
    for (int r = 0; r < 16; ++r) {
        pe[r] = __expf(part[r] + bv0);
        sloc += pe[r];
    }
    if (m < 16) {
        int r = m;
        int rowi = (r & 3) + 8*(r >> 2) + 4*kh;      // validated C/D row map
        p_out[row0 + w*32 + rowi] = pe[r];
    }
    float stot = sloc + __shfl_xor(sloc, 32);        // half0 rows + half1 rows
    if (L == 0) atomicAdd(&Ssum[b], stot);

    // ---- P.V from the staged f16 tile: c_w[vd=L*4..+4) = sum_t p_t * V[t][vd]
    f32x4 cw = {};
    #pragma unroll
    for (int t = 0; t < 32; ++t) {
        int h = (t >> 2) & 1;
        int r = (t & 3) + 4*(t >> 3);                // row(r,h) == t
        float pt = __shfl(pe[r], h*32);              // broadcast from the right half
        half4v v4 = *(const half4v*)(Vw + t*512 + (((L>>1) ^ (t & 7))*16) + (L & 1)*8);
        cw[0] += pt*(float)v4[0]; cw[1] += pt*(float)v4[1];
        cw[2] += pt*(float)v4[2]; cw[3] += pt*(float)v4[3];
    }

    // ---- combine the 4 wave partials in LDS, one atomicAdd per (b, vd)
    __syncthreads();                                 // all waves done reading V
    ((f32x4*)Vw)[L] = cw;                            // reuse own region
    __syncthreads();
    const float* Vf = (const float*)Vraw;
    float tot = Vf[tid] + Vf[4096 + tid] + Vf[8192 + tid] + Vf[12288 + tid];
    atomicAdd(&cout[b*DD + tid], tot);
}

// ---------------------------------------------------------------------------
// Kernel 2: normalize. blocks 0..31: a[b,:] /= S[b]; block 32: c /= S[b].
// ---------------------------------------------------------------------------
__global__ __launch_bounds__(256) void finalize_kernel(
    float* __restrict__ out_c, float* __restrict__ out_a,
    const float* __restrict__ Ssum)
{
    int blk = blockIdx.x, tid = threadIdx.x;
    if (blk < BB) {
        float inv = 1.f / Ssum[blk];
        f32x4* ap = (f32x4*)(out_a + blk*TT);
        #pragma unroll
        for (int i = 0; i < 4; ++i) {
            f32x4 v = ap[i*256 + tid];
            v[0]*=inv; v[1]*=inv; v[2]*=inv; v[3]*=inv;
            ap[i*256 + tid] = v;
        }
    } else {
        f32x4* cp = (f32x4*)out_c;
        #pragma unroll
        for (int i = 0; i < 8; ++i) {
            int idx = i*256 + tid;       // f32x4 index, 64 per batch
            float inv = 1.f / Ssum[idx >> 6];
            f32x4 v = cp[idx];
            v[0]*=inv; v[1]*=inv; v[2]*=inv; v[3]*=inv;
            cp[idx] = v;
        }
    }
}

// ---------------------------------------------------------------------------
extern "C" void kernel_launch(void* const* d_in, const int* in_sizes, int n_in,
                              void* d_out, int out_size, void* d_ws, size_t ws_size,
                              hipStream_t stream)
{
    (void)in_sizes; (void)n_in; (void)out_size; (void)ws_size;
    const float* query  = (const float*)d_in[0];
    const float* values = (const float*)d_in[1];
    const float* Wq     = (const float*)d_in[2];
    const float* bq     = (const float*)d_in[3];
    const float* Wv     = (const float*)d_in[4];
    const float* bv     = (const float*)d_in[5];
    const float* wvs    = (const float*)d_in[6];
    const float* bvs    = (const float*)d_in[7];

    float* out  = (float*)d_out;
    float* cptr = out;             // [32,256]
    float* aptr = out + BB*DD;     // [32,4096] (unnormalized p, then a)

    float* qp     = (float*)d_ws;                          // 32 KB
    half8* wvfrag = (half8*)((char*)d_ws + BB*DD*4);       // 128 KB
    float* Ssum   = (float*)((char*)d_ws + BB*DD*4 + 131072); // 128 B

    hipMemsetAsync(cptr, 0, BB*DD*sizeof(float), stream);
    hipMemsetAsync(Ssum, 0, BB*sizeof(float), stream);
    prep_kernel<<<64, 256, 0, stream>>>(query, Wq, bq, Wv, bv, qp, wvfrag);
    fused_kernel<<<TT*BB/128, 256, 0, stream>>>(values, wvfrag, qp, wvs, bvs,
                                                aptr, cptr, Ssum);
    finalize_kernel<<<BB + 1, 256, 0, stream>>>(cptr, aptr, Ssum);
}

// Round 3
// 265.076 us; speedup vs baseline: 1.2483x; 1.2483x over previous
//
#include <hip/hip_runtime.h>
#include <hip/hip_bf16.h>
#include <hip/hip_fp16.h>

// Bahdanau attention: B=32, T=4096, QD=VD=AD=256
// out = (c [32,256], a [32,4096]) fp32, concatenated flat.
//
// Round 3: transposed fused GEMM. A-operand = Wv (a-rows), B-operand = values
// (t-cols). C-layout puts a in registers -> Sum_a wv*tanh is in-lane (+1 shfl).
// B-frags (values) held in 64 VGPRs per wave, reused across all 8 a-tiles;
// Wv streams through a 16KB LDS chunk (prefetch-pipelined); V staged once in
// 64KB LDS (fully swizzled, conflict-free); P.V fused from the LDS V-tile.

#define BB 32
#define TT 4096
#define DD 256

typedef _Float16 half8  __attribute__((ext_vector_type(8)));
typedef _Float16 half4v __attribute__((ext_vector_type(4)));
typedef float f32x2  __attribute__((ext_vector_type(2)));
typedef float f32x4  __attribute__((ext_vector_type(4)));
typedef float f32x16 __attribute__((ext_vector_type(16)));

// full 5-bit swizzle of the 16B-group index within a 512B row: conflict-free
// for 32-row windows in every access pattern used below.
__device__ __forceinline__ int swz(int row, int g) {
    return g ^ (row & 7) ^ (((row >> 3) & 3) << 3);
}

__device__ __forceinline__ float tanh_fast(float x) {
    float ex = __expf(2.f*x);
    return __builtin_fmaf(-2.f, __builtin_amdgcn_rcpf(ex + 1.f), 1.f);
}

// ---------------------------------------------------------------------------
// Kernel 0: prep.
//  blocks 0..31 : qw[b,a] = { query[b,:].Wq[a,:] + bq[a] + bv[a], wvs[a] }
//  blocks 32..63: Wv fp32 -> f16, PLAIN row-major [a][k]
// ---------------------------------------------------------------------------
__global__ __launch_bounds__(256) void prep_kernel(
    const float* __restrict__ query, const float* __restrict__ Wq,
    const float* __restrict__ bq,    const float* __restrict__ Wv,
    const float* __restrict__ bv,    const float* __restrict__ wvs,
    f32x2* __restrict__ qw, half8* __restrict__ wvh)
{
    int blk = blockIdx.x, tid = threadIdx.x;
    if (blk < BB) {
        __shared__ float ql[DD];
        ql[tid] = query[blk*DD + tid];
        __syncthreads();
        const f32x4* wr4 = (const f32x4*)(Wq + tid*DD);
        const f32x4* ql4 = (const f32x4*)ql;
        float s = 0.f;
        #pragma unroll 8
        for (int q = 0; q < DD/4; ++q) {
            f32x4 w4 = wr4[q];
            f32x4 x4 = ql4[q];
            s += w4[0]*x4[0] + w4[1]*x4[1] + w4[2]*x4[2] + w4[3]*x4[3];
        }
        f32x2 o;
        o[0] = s + bq[tid] + bv[tid];
        o[1] = wvs[tid];
        qw[blk*DD + tid] = o;
    } else {
        int e0 = (blk - BB)*2048 + tid*8;
        f32x4 s0 = *(const f32x4*)(Wv + e0);
        f32x4 s1 = *(const f32x4*)(Wv + e0 + 4);
        half8 h;
        h[0]=(_Float16)s0[0]; h[1]=(_Float16)s0[1]; h[2]=(_Float16)s0[2]; h[3]=(_Float16)s0[3];
        h[4]=(_Float16)s1[0]; h[5]=(_Float16)s1[1]; h[6]=(_Float16)s1[2]; h[7]=(_Float16)s1[3];
        wvh[e0 >> 3] = h;
    }
}

// ---------------------------------------------------------------------------
// Kernel 1: fused. 1024 blocks x 256 threads (4 waves). Block: 128 t-rows.
// Wave w owns t-slice [w*32, +32). LDS: V 64KB + Wv-chunk 16KB = 80KB
// (2 blocks/CU). MFMA 32x32x16_f16: D[row=a][col=t].
// ---------------------------------------------------------------------------
__global__ __launch_bounds__(256, 2) void fused_kernel(
    const float* __restrict__ values, const half8* __restrict__ wvh,
    const f32x2* __restrict__ qw,     const float* __restrict__ bvs,
    float* __restrict__ p_out,        float* __restrict__ cout,
    float* __restrict__ Ssum)
{
    __shared__ char lds[81920];
    char* Vl = lds;            // 64 KB: 128 rows x 512B (f16, swizzled)
    char* Cl = lds + 65536;    // 16 KB: Wv chunk (reused for c-combine)

    int tid = threadIdx.x;
    int w = tid >> 6, L = tid & 63;
    int tl = L & 31, kh = L >> 5;
    int row0 = blockIdx.x * 128;
    int b = row0 >> 12;

    // ---- stage V: 128 rows x 256 f32 -> f16, coalesced, swizzled.
    const float* gv = values + (size_t)row0 * DD;
    #pragma unroll
    for (int bt = 0; bt < 4; ++bt) {
        f32x4 ld[8];
        #pragma unroll
        for (int i = 0; i < 8; ++i)
            ld[i] = *(const f32x4*)(gv + (bt*8 + i)*1024 + tid*4);
        #pragma unroll
        for (int i = 0; i < 8; ++i) {
            int row = (bt*8 + i)*4 + (tid >> 6);
            f32x4 v4 = ld[i];
            half4v h;
            h[0]=(_Float16)v4[0]; h[1]=(_Float16)v4[1];
            h[2]=(_Float16)v4[2]; h[3]=(_Float16)v4[3];
            *(half4v*)(Vl + row*512 + swz(row, L >> 1)*16 + (L & 1)*8) = h;
        }
    }
    __syncthreads();

    // ---- B-frags (values): 16 k-steps held in registers, reused 8x.
    int t = w*32 + tl;
    half8 bf[16];
    #pragma unroll
    for (int kk = 0; kk < 16; ++kk)
        bf[kk] = *(const half8*)(Vl + t*512 + swz(t, kk*2 + kh)*16);

    float e_acc = 0.f;
    const f32x2* qwb = qw + b*DD;

    // prefetch chunk 0
    half8 pre[4];
    #pragma unroll
    for (int i = 0; i < 4; ++i)
        pre[i] = wvh[i*256 + tid];

    for (int ch = 0; ch < 8; ++ch) {
        __syncthreads();                 // readers done with previous chunk
        #pragma unroll
        for (int i = 0; i < 4; ++i) {
            int row = i*8 + (tid >> 5);
            *(half8*)(Cl + row*512 + swz(row, tid & 31)*16) = pre[i];
        }
        if (ch < 7) {
            #pragma unroll
            for (int i = 0; i < 4; ++i)
                pre[i] = wvh[(ch + 1)*1024 + i*256 + tid];
        }
        __syncthreads();

        // A-frags (Wv chunk) + MFMA
        half8 af[16];
        #pragma unroll
        for (int kk = 0; kk < 16; ++kk)
            af[kk] = *(const half8*)(Cl + tl*512 + swz(tl, kk*2 + kh)*16);
        f32x16 acc = {};
        #pragma unroll
        for (int kk = 0; kk < 16; ++kk)
            acc = __builtin_amdgcn_mfma_f32_32x32x16_f16(af[kk], bf[kk], acc, 0, 0, 0);

        // in-lane epilogue: e += wv[a] * tanh(K[a][t] + qp[a])
        #pragma unroll
        for (int r = 0; r < 16; ++r) {
            int a = ch*32 + (r & 3) + 8*(r >> 2) + 4*kh;
            f32x2 q2 = qwb[a];
            e_acc += q2[1] * tanh_fast(acc[r] + q2[0]);
        }
    }

    // ---- combine kh halves, p = exp(e), Ssum
    e_acc += __shfl_xor(e_acc, 32);
    float p = __expf(e_acc + bvs[0]);
    if (kh == 0) p_out[row0 + w*32 + tl] = p;
    float s = p;
    s += __shfl_xor(s, 1);
    s += __shfl_xor(s, 2);
    s += __shfl_xor(s, 4);
    s += __shfl_xor(s, 8);
    s += __shfl_xor(s, 16);
    if (L == 0) atomicAdd(&Ssum[b], s);

    // ---- P.V from the staged V tile (wave-local rows; p via v_readlane)
    f32x4 cw = {};
    #pragma unroll
    for (int t2 = 0; t2 < 32; ++t2) {
        int rt = w*32 + t2;
        float pt = __shfl(p, t2);
        half4v v4 = *(const half4v*)(Vl + rt*512 + swz(rt, L >> 1)*16 + (L & 1)*8);
        cw[0] += pt*(float)v4[0]; cw[1] += pt*(float)v4[1];
        cw[2] += pt*(float)v4[2]; cw[3] += pt*(float)v4[3];
    }

    // ---- cross-wave combine in Cl (chunk area now dead), 1 atomic per elem
    __syncthreads();
    *(f32x4*)(Cl + (w*64 + L)*16) = cw;
    __syncthreads();
    if (tid < 64) {
        const f32x4* cc = (const f32x4*)Cl;
        f32x4 tot = cc[tid];
        f32x4 a1 = cc[64 + tid], a2 = cc[128 + tid], a3 = cc[192 + tid];
        tot[0] += a1[0] + a2[0] + a3[0];
        tot[1] += a1[1] + a2[1] + a3[1];
        tot[2] += a1[2] + a2[2] + a3[2];
        tot[3] += a1[3] + a2[3] + a3[3];
        #pragma unroll
        for (int j = 0; j < 4; ++j)
            atomicAdd(&cout[b*DD + tid*4 + j], tot[j]);
    }
}

// ---------------------------------------------------------------------------
// Kernel 2: normalize. blocks 0..31: a[b,:] /= S[b]; block 32: c /= S[b].
// ---------------------------------------------------------------------------
__global__ __launch_bounds__(256) void finalize_kernel(
    float* __restrict__ out_c, float* __restrict__ out_a,
    const float* __restrict__ Ssum)
{
    int blk = blockIdx.x, tid = threadIdx.x;
    if (blk < BB) {
        float inv = 1.f / Ssum[blk];
        f32x4* ap = (f32x4*)(out_a + blk*TT);
        #pragma unroll
        for (int i = 0; i < 4; ++i) {
            f32x4 v = ap[i*256 + tid];
            v[0]*=inv; v[1]*=inv; v[2]*=inv; v[3]*=inv;
            ap[i*256 + tid] = v;
        }
    } else {
        f32x4* cp = (f32x4*)out_c;
        #pragma unroll
        for (int i = 0; i < 8; ++i) {
            int idx = i*256 + tid;       // f32x4 index, 64 per batch
            float inv = 1.f / Ssum[idx >> 6];
            f32x4 v = cp[idx];
            v[0]*=inv; v[1]*=inv; v[2]*=inv; v[3]*=inv;
            cp[idx] = v;
        }
    }
}

// ---------------------------------------------------------------------------
extern "C" void kernel_launch(void* const* d_in, const int* in_sizes, int n_in,
                              void* d_out, int out_size, void* d_ws, size_t ws_size,
                              hipStream_t stream)
{
    (void)in_sizes; (void)n_in; (void)out_size; (void)ws_size;
    const float* query  = (const float*)d_in[0];
    const float* values = (const float*)d_in[1];
    const float* Wq     = (const float*)d_in[2];
    const float* bq     = (const float*)d_in[3];
    const float* Wv     = (const float*)d_in[4];
    const float* bv     = (const float*)d_in[5];
    const float* wvs    = (const float*)d_in[6];
    const float* bvs    = (const float*)d_in[7];

    float* out  = (float*)d_out;
    float* cptr = out;             // [32,256]
    float* aptr = out + BB*DD;     // [32,4096] (unnormalized p, then a)

    f32x2* qw   = (f32x2*)d_ws;                              // 64 KB
    half8* wvh  = (half8*)((char*)d_ws + 65536);             // 128 KB
    float* Ssum = (float*)((char*)d_ws + 65536 + 131072);    // 128 B

    hipMemsetAsync(cptr, 0, BB*DD*sizeof(float), stream);
    hipMemsetAsync(Ssum, 0, BB*sizeof(float), stream);
    prep_kernel<<<64, 256, 0, stream>>>(query, Wq, bq, Wv, bv, wvs, qw, wvh);
    fused_kernel<<<TT*BB/128, 256, 0, stream>>>(values, wvh, qw, bvs,
                                                aptr, cptr, Ssum);
    finalize_kernel<<<BB + 1, 256, 0, stream>>>(cptr, aptr, Ssum);
}